// Round 1
// baseline (1426.651 us; speedup 1.0000x reference)
//
#include <hip/hip_runtime.h>

// ---------------- problem constants ----------------
constexpr int B_   = 32;
constexpr int CIN  = 256;
constexpr int HW   = 56 * 56;      // 3136
constexpr int BOT  = 128;
constexpr int GRW  = 32;
constexpr int COUT = CIN + GRW;    // 288
constexpr int NBATCH = B_ * CIN * HW;   // 25,690,112
constexpr int NX2    = B_ * BOT * HW;   // 12,845,056
constexpr int NOUT   = B_ * COUT * HW;  // 28,901,376

// ---------------- workspace layout (floats unless noted) ----------------
// scal (16 u32): [0]=max_x1 [1]=max|batch| [2]=max_x2 [3]=max|x3|
constexpr int OFF_W1Q = 16;
constexpr int OFF_B1Q = OFF_W1Q + 256;            // 272
constexpr int OFF_WFQ = OFF_B1Q + 256;            // 528
constexpr int OFF_BFQ = OFF_WFQ + BOT * CIN;      // 33296
constexpr int OFF_W2Q = OFF_BFQ + BOT;            // 33424
constexpr int OFF_SMALL_END = OFF_W2Q + GRW * BOT * 9;   // 70288
constexpr size_t X1Q_BYTE = (size_t)OFF_SMALL_END * 4;   // int8 x1q, NBATCH bytes
constexpr size_t X2_BYTE  = X1Q_BYTE + (size_t)NBATCH;   // fp32 x2
constexpr size_t X3_BYTE  = X2_BYTE + (size_t)NX2 * 4;   // fp32 x3

__device__ __forceinline__ float blockReduceMax256(float v) {
    #pragma unroll
    for (int o = 32; o > 0; o >>= 1) v = fmaxf(v, __shfl_down(v, o, 64));
    __shared__ float sm[4];
    if ((threadIdx.x & 63) == 0) sm[threadIdx.x >> 6] = v;
    __syncthreads();
    return fmaxf(fmaxf(sm[0], sm[1]), fmaxf(sm[2], sm[3]));
}

__device__ __forceinline__ float clamp8(float r) {
    return fminf(fmaxf(r, -128.0f), 127.0f);
}
__device__ __forceinline__ float clampBig(float r) {
    return fminf(fmaxf(r, -2147483648.0f), 2147483648.0f);
}

// ---------------- prep1: zero scalars, BN1 folded quant weights ----------------
__global__ void prep1_kernel(const float* __restrict__ g1, const float* __restrict__ b1p,
                             const float* __restrict__ m1, const float* __restrict__ v1,
                             const float* __restrict__ s_in_p, float* __restrict__ ws) {
    int c = threadIdx.x;
    unsigned* scal = (unsigned*)ws;
    if (c < 16) scal[c] = 0u;
    float s_in = *s_in_p;
    float r = 1.0f / sqrtf(v1[c] + 1e-5f);
    float w1 = __fmul_rn(g1[c], r);
    float b1 = __fsub_rn(b1p[c], __fmul_rn(m1[c], w1));
    float mx = blockReduceMax256(fabsf(w1));
    float s_bn = mx / 127.0f + 1e-8f;
    ws[OFF_W1Q + c] = __fmul_rn(clamp8(rintf(w1 / s_bn)), s_bn);
    float sb = __fmul_rn(s_in, s_bn);
    ws[OFF_B1Q + c] = __fmul_rn(clampBig(rintf(b1 / sb)), sb);
}

// ---------------- pass 1: max of relu(bn1(batch)) and max|batch| ----------------
__global__ __launch_bounds__(256) void max1_kernel(const float4* __restrict__ batch4,
                                                   float* __restrict__ ws) {
    const float* w1q = ws + OFF_W1Q;
    const float* b1q = ws + OFF_B1Q;
    int n4 = NBATCH / 4;   // 6,422,528
    float mx1 = 0.0f, mxb = 0.0f;
    for (int i = blockIdx.x * blockDim.x + threadIdx.x; i < n4; i += gridDim.x * blockDim.x) {
        int c = (i / 784) & 255;
        float w = w1q[c], b = b1q[c];
        float4 v = batch4[i];
        float x0 = fmaxf(__fadd_rn(__fmul_rn(v.x, w), b), 0.0f);
        float x1 = fmaxf(__fadd_rn(__fmul_rn(v.y, w), b), 0.0f);
        float x2 = fmaxf(__fadd_rn(__fmul_rn(v.z, w), b), 0.0f);
        float x3 = fmaxf(__fadd_rn(__fmul_rn(v.w, w), b), 0.0f);
        mx1 = fmaxf(mx1, fmaxf(fmaxf(x0, x1), fmaxf(x2, x3)));
        mxb = fmaxf(mxb, fmaxf(fmaxf(fabsf(v.x), fabsf(v.y)), fmaxf(fabsf(v.z), fabsf(v.w))));
    }
    mx1 = blockReduceMax256(mx1);
    __syncthreads();
    mxb = blockReduceMax256(mxb);
    if (threadIdx.x == 0) {
        atomicMax((unsigned*)ws + 0, __float_as_uint(mx1));
        atomicMax((unsigned*)ws + 1, __float_as_uint(mxb));
    }
}

// ---------------- quantize x1 -> int8 ----------------
__global__ __launch_bounds__(256) void quant1_kernel(const float4* __restrict__ batch4,
                                                     float* __restrict__ ws) {
    const float* w1q = ws + OFF_W1Q;
    const float* b1q = ws + OFF_B1Q;
    unsigned* x1q4 = (unsigned*)((char*)ws + X1Q_BYTE);
    float s_a1 = __uint_as_float(((unsigned*)ws)[0]) / 127.0f + 1e-8f;
    int n4 = NBATCH / 4;
    for (int i = blockIdx.x * blockDim.x + threadIdx.x; i < n4; i += gridDim.x * blockDim.x) {
        int c = (i / 784) & 255;
        float w = w1q[c], b = b1q[c];
        float4 v = batch4[i];
        unsigned n0 = (unsigned)(int)clamp8(rintf(fmaxf(__fadd_rn(__fmul_rn(v.x, w), b), 0.0f) / s_a1));
        unsigned n1 = (unsigned)(int)clamp8(rintf(fmaxf(__fadd_rn(__fmul_rn(v.y, w), b), 0.0f) / s_a1));
        unsigned n2 = (unsigned)(int)clamp8(rintf(fmaxf(__fadd_rn(__fmul_rn(v.z, w), b), 0.0f) / s_a1));
        unsigned n3 = (unsigned)(int)clamp8(rintf(fmaxf(__fadd_rn(__fmul_rn(v.w, w), b), 0.0f) / s_a1));
        x1q4[i] = n0 | (n1 << 8) | (n2 << 16) | (n3 << 24);
    }
}

// ---------------- prep2: fold bn2 into conv1 w, quant; quant conv2 w ----------------
__global__ void prep2_kernel(const float* __restrict__ c1w,
                             const float* __restrict__ g2, const float* __restrict__ b2,
                             const float* __restrict__ m2, const float* __restrict__ v2,
                             const float* __restrict__ c2w, float* __restrict__ ws) {
    int bi = blockIdx.x;
    int tid = threadIdx.x;
    if (bi < BOT) {
        int o = bi;
        float t = __fmul_rn(g2[o], 1.0f / sqrtf(v2[o] + 1e-5f));
        float wf = __fmul_rn(c1w[o * CIN + tid], t);
        float mx = blockReduceMax256(fabsf(wf));
        float s_w1 = mx / 127.0f + 1e-8f;
        ws[OFF_WFQ + o * CIN + tid] = __fmul_rn(clamp8(rintf(wf / s_w1)), s_w1);
        if (tid == 0) {
            float s_a1 = __uint_as_float(((unsigned*)ws)[0]) / 127.0f + 1e-8f;
            float bf = __fsub_rn(b2[o], __fmul_rn(m2[o], t));
            float sb = __fmul_rn(s_a1, s_w1);
            ws[OFF_BFQ + o] = __fmul_rn(clampBig(rintf(bf / sb)), sb);
        }
    } else {
        int g = bi - BOT;               // conv2 out channel
        float mx = 0.0f;
        for (int s = tid; s < BOT * 9; s += 256) mx = fmaxf(mx, fabsf(c2w[g * BOT * 9 + s]));
        mx = blockReduceMax256(mx);
        float s_w2 = mx / 127.0f + 1e-8f;
        for (int s = tid; s < BOT * 9; s += 256) {
            float w = c2w[g * BOT * 9 + s];
            ws[OFF_W2Q + g * BOT * 9 + s] = __fmul_rn(clamp8(rintf(w / s_w2)), s_w2);
        }
    }
}

// ---------------- conv1: 1x1, x1q(int8) x wfq -> x2 (relu), track max ----------------
__global__ __launch_bounds__(256) void conv1_kernel(float* __restrict__ ws) {
    __shared__ float lx[64][64];    // [c_local][hw]  16 KB
    __shared__ float lw[128][64];   // [o][c_local]   32 KB
    const unsigned char* x1q = (const unsigned char*)((char*)ws + X1Q_BYTE);
    const float* wfq = ws + OFF_WFQ;
    const float* bfq = ws + OFF_BFQ;
    float* x2 = (float*)((char*)ws + X2_BYTE);
    int bi = blockIdx.x;
    int b = bi / 49;
    int hw0 = (bi % 49) * 64;
    int tid = threadIdx.x;
    int hw = tid & 63;
    int ob = (tid >> 6) * 32;
    float s_a1 = __uint_as_float(((unsigned*)ws)[0]) / 127.0f + 1e-8f;
    float acc[32];
    #pragma unroll
    for (int i = 0; i < 32; i++) acc[i] = 0.0f;

    for (int kc = 0; kc < CIN; kc += 64) {
        __syncthreads();
        {   // x tile: 64 c x 64 hw, int8 -> dequant
            int cl = tid >> 4;              // 0..15
            int hl = (tid & 15) << 2;       // 0,4,...,60
            #pragma unroll
            for (int j = 0; j < 4; j++) {
                int c = cl + j * 16;
                unsigned p = *(const unsigned*)(x1q + (size_t)(b * CIN + kc + c) * HW + hw0 + hl);
                lx[c][hl + 0] = __fmul_rn((float)(p & 255u), s_a1);
                lx[c][hl + 1] = __fmul_rn((float)((p >> 8) & 255u), s_a1);
                lx[c][hl + 2] = __fmul_rn((float)((p >> 16) & 255u), s_a1);
                lx[c][hl + 3] = __fmul_rn((float)(p >> 24), s_a1);
            }
        }
        {   // w tile: 128 o x 64 c
            int c = tid & 63;
            int o0 = tid >> 6;              // 0..3
            #pragma unroll
            for (int j = 0; j < 32; j++) {
                int o = o0 + j * 4;
                lw[o][c] = wfq[o * CIN + kc + c];
            }
        }
        __syncthreads();
        #pragma unroll 4
        for (int c = 0; c < 64; c++) {
            float xv = lx[c][hw];
            #pragma unroll
            for (int oo = 0; oo < 32; oo++)
                acc[oo] = fmaf(xv, lw[ob + oo][c], acc[oo]);
        }
    }
    float mx = 0.0f;
    #pragma unroll
    for (int oo = 0; oo < 32; oo++) {
        int o = ob + oo;
        float v = fmaxf(__fadd_rn(acc[oo], bfq[o]), 0.0f);
        mx = fmaxf(mx, v);
        x2[(size_t)(b * BOT + o) * HW + hw0 + hw] = v;
    }
    mx = blockReduceMax256(mx);
    if (threadIdx.x == 0) atomicMax((unsigned*)ws + 2, __float_as_uint(mx));
}

// ---------------- conv2: 3x3, quant(x2) x w2q -> x3, track max|x3| ----------------
__global__ __launch_bounds__(256) void conv2_kernel(float* __restrict__ ws) {
    __shared__ float xt[16 * 6 * 58];    // [c][row 0..5][w58]  22.3 KB
    __shared__ float wt[32 * 16 * 9];    // [g][c][k]           18.4 KB
    const float* x2 = (const float*)((char*)ws + X2_BYTE);
    const float* w2q = ws + OFF_W2Q;
    float* x3 = (float*)((char*)ws + X3_BYTE);
    int bi = blockIdx.x;
    int b = bi / 14;
    int h0 = (bi % 14) * 4;
    int tid = threadIdx.x;
    int w = tid & 63;
    int hl = tid >> 6;       // 0..3
    bool valid = (w < 56);
    int wc = min(w, 55);
    float s_a2 = __uint_as_float(((unsigned*)ws)[2]) / 127.0f + 1e-8f;
    float acc[32];
    #pragma unroll
    for (int i = 0; i < 32; i++) acc[i] = 0.0f;

    for (int c0 = 0; c0 < BOT; c0 += 16) {
        __syncthreads();
        for (int s = tid; s < 16 * 6 * 58; s += 256) {
            int c = s / 348;
            int rr = (s - c * 348) / 58;
            int w58 = s - c * 348 - rr * 58;
            int x = w58 - 1;
            int h = h0 + rr - 1;
            float v = 0.0f;
            if (x >= 0 && x < 56 && h >= 0 && h < 56) {
                float raw = x2[(size_t)(b * BOT + c0 + c) * HW + h * 56 + x];
                float q = clamp8(rintf(raw / s_a2));
                v = __fmul_rn(q, s_a2);
            }
            xt[s] = v;
        }
        for (int s = tid; s < 32 * 16 * 9; s += 256) {
            int g = s / 144;
            int j = s - g * 144;
            wt[s] = w2q[g * (BOT * 9) + c0 * 9 + j];
        }
        __syncthreads();
        #pragma unroll
        for (int c = 0; c < 16; c++) {
            #pragma unroll
            for (int kh = 0; kh < 3; kh++) {
                const float* xr = &xt[c * 348 + (hl + kh) * 58 + wc];
                float xv0 = xr[0], xv1 = xr[1], xv2 = xr[2];
                const float* wr = &wt[c * 9 + kh * 3];
                #pragma unroll
                for (int g = 0; g < 32; g++) {
                    const float* wg = wr + g * 144;
                    acc[g] = fmaf(xv0, wg[0], acc[g]);
                    acc[g] = fmaf(xv1, wg[1], acc[g]);
                    acc[g] = fmaf(xv2, wg[2], acc[g]);
                }
            }
        }
    }
    float mx = 0.0f;
    int hout = h0 + hl;
    #pragma unroll
    for (int g = 0; g < 32; g++) {
        mx = fmaxf(mx, fabsf(acc[g]));
        if (valid) x3[(size_t)(b * GRW + g) * HW + hout * 56 + w] = acc[g];
    }
    mx = blockReduceMax256(mx);
    if (threadIdx.x == 0) atomicMax((unsigned*)ws + 3, __float_as_uint(mx));
}

// ---------------- output: concat + fake-quant ----------------
__global__ __launch_bounds__(256) void outq_kernel(const float4* __restrict__ batch4,
                                                   const float* __restrict__ ws,
                                                   float* __restrict__ out) {
    const float4* x34 = (const float4*)((const char*)ws + X3_BYTE);
    float maxb = __uint_as_float(((const unsigned*)ws)[1]);
    float max3 = __uint_as_float(((const unsigned*)ws)[3]);
    float s_out = fmaxf(maxb, max3) / 127.0f + 1e-8f;
    float4* out4 = (float4*)out;
    int n4 = NOUT / 4;   // 7,225,344
    for (int i = blockIdx.x * blockDim.x + threadIdx.x; i < n4; i += gridDim.x * blockDim.x) {
        int chl = i / 784;
        int b = chl / COUT;
        int ch = chl - b * COUT;
        int hw4 = i - chl * 784;
        float4 v;
        if (ch < CIN) v = batch4[(b * CIN + ch) * 784 + hw4];
        else          v = x34[(b * GRW + (ch - CIN)) * 784 + hw4];
        float4 r;
        r.x = __fmul_rn(clamp8(rintf(v.x / s_out)), s_out);
        r.y = __fmul_rn(clamp8(rintf(v.y / s_out)), s_out);
        r.z = __fmul_rn(clamp8(rintf(v.z / s_out)), s_out);
        r.w = __fmul_rn(clamp8(rintf(v.w / s_out)), s_out);
        out4[i] = r;
    }
    if (blockIdx.x == 0 && threadIdx.x == 0) out[NOUT] = s_out;
}

extern "C" void kernel_launch(void* const* d_in, const int* in_sizes, int n_in,
                              void* d_out, int out_size, void* d_ws, size_t ws_size,
                              hipStream_t stream) {
    const float* batch = (const float*)d_in[0];
    const float* s_in  = (const float*)d_in[1];
    const float* g1    = (const float*)d_in[2];
    const float* b1    = (const float*)d_in[3];
    const float* m1    = (const float*)d_in[4];
    const float* v1    = (const float*)d_in[5];
    const float* c1w   = (const float*)d_in[6];
    const float* g2    = (const float*)d_in[7];
    const float* b2    = (const float*)d_in[8];
    const float* m2    = (const float*)d_in[9];
    const float* v2    = (const float*)d_in[10];
    const float* c2w   = (const float*)d_in[11];
    float* out = (float*)d_out;
    float* ws  = (float*)d_ws;

    hipLaunchKernelGGL(prep1_kernel, dim3(1), dim3(256), 0, stream, g1, b1, m1, v1, s_in, ws);
    hipLaunchKernelGGL(max1_kernel, dim3(4096), dim3(256), 0, stream, (const float4*)batch, ws);
    hipLaunchKernelGGL(quant1_kernel, dim3(4096), dim3(256), 0, stream, (const float4*)batch, ws);
    hipLaunchKernelGGL(prep2_kernel, dim3(160), dim3(256), 0, stream, c1w, g2, b2, m2, v2, c2w, ws);
    hipLaunchKernelGGL(conv1_kernel, dim3(32 * 49), dim3(256), 0, stream, ws);
    hipLaunchKernelGGL(conv2_kernel, dim3(32 * 14), dim3(256), 0, stream, ws);
    hipLaunchKernelGGL(outq_kernel, dim3(4096), dim3(256), 0, stream, (const float4*)batch, ws, out);
}

// Round 4
// 534.216 us; speedup vs baseline: 2.6705x; 2.6705x over previous
//
#include <hip/hip_runtime.h>

typedef __attribute__((ext_vector_type(8))) short bf16x8;
typedef __attribute__((ext_vector_type(4))) float f32x4;

// ---------------- problem constants ----------------
constexpr int B_   = 32;
constexpr int CIN  = 256;
constexpr int HW   = 56 * 56;      // 3136
constexpr int BOT  = 128;
constexpr int GRW  = 32;
constexpr int COUT = CIN + GRW;    // 288
constexpr int NBATCH = B_ * CIN * HW;   // 25,690,112
constexpr int NX2    = B_ * BOT * HW;   // 12,845,056
constexpr int NOUT   = B_ * COUT * HW;  // 28,901,376

// ---------------- workspace layout (float units unless noted) ----------------
// scal u32: [0]=max_x1 [1]=max|batch| [2]=max_x2 [3]=max|x3|
constexpr int OFF_W1Q  = 16;
constexpr int OFF_B1Q  = OFF_W1Q + 256;
constexpr int OFF_BFQ  = OFF_B1Q + 256;          // 128 floats
constexpr int OFF_SC1  = OFF_BFQ + 128;          // 128 floats  (s_a1*s_w1[o])
constexpr int OFF_SC2  = OFF_SC1 + 128;          // 32 floats   (s_w2[g])
constexpr int OFF_WQ1B = OFF_SC2 + 32;           // ushort[128*256] = 16384 floats
constexpr int OFF_W2B  = OFF_WQ1B + 16384;       // ushort[9*32*128] = 18432 floats
constexpr int OFF_END  = OFF_W2B + 18432;        // = 35632 floats
constexpr size_t X1Q_BYTE = (size_t)OFF_END * 4;          // int8 x1q [b][hw][c]
constexpr size_t X2_BYTE  = X1Q_BYTE + (size_t)NBATCH;    // fp32 x2 [b][o][hw]
constexpr size_t X3_BYTE  = X2_BYTE + (size_t)NX2 * 4;    // fp32 x3 [b][g][hw]

__device__ __forceinline__ float blockReduceMax256(float v) {
    #pragma unroll
    for (int o = 32; o > 0; o >>= 1) v = fmaxf(v, __shfl_down(v, o, 64));
    __shared__ float sm[4];
    if ((threadIdx.x & 63) == 0) sm[threadIdx.x >> 6] = v;
    __syncthreads();
    return fmaxf(fmaxf(sm[0], sm[1]), fmaxf(sm[2], sm[3]));
}
__device__ __forceinline__ float waveReduceMax(float v) {
    #pragma unroll
    for (int o = 32; o > 0; o >>= 1) v = fmaxf(v, __shfl_down(v, o, 64));
    return v;
}
__device__ __forceinline__ float clamp8(float r)   { return fminf(fmaxf(r, -128.0f), 127.0f); }
__device__ __forceinline__ float clampBig(float r) { return fminf(fmaxf(r, -2147483648.0f), 2147483648.0f); }
__device__ __forceinline__ unsigned short bf16u(float f) { return (unsigned short)(__float_as_uint(f) >> 16); }

// ---------------- prep1: zero scalars, BN1 folded quant weights ----------------
__global__ void prep1_kernel(const float* __restrict__ g1, const float* __restrict__ b1p,
                             const float* __restrict__ m1, const float* __restrict__ v1,
                             const float* __restrict__ s_in_p, float* __restrict__ ws) {
    int c = threadIdx.x;
    unsigned* scal = (unsigned*)ws;
    if (c < 16) scal[c] = 0u;
    float s_in = *s_in_p;
    float r = 1.0f / sqrtf(v1[c] + 1e-5f);
    float w1 = __fmul_rn(g1[c], r);
    float b1 = __fsub_rn(b1p[c], __fmul_rn(m1[c], w1));
    float mx = blockReduceMax256(fabsf(w1));
    float s_bn = mx / 127.0f + 1e-8f;
    ws[OFF_W1Q + c] = __fmul_rn(clamp8(rintf(w1 / s_bn)), s_bn);
    float sb = __fmul_rn(s_in, s_bn);
    ws[OFF_B1Q + c] = __fmul_rn(clampBig(rintf(b1 / sb)), sb);
}

// ---------------- pass 1: max of relu(bn1(batch)) and max|batch| ----------------
__global__ __launch_bounds__(256) void max1_kernel(const float4* __restrict__ batch4,
                                                   float* __restrict__ ws) {
    const float* w1q = ws + OFF_W1Q;
    const float* b1q = ws + OFF_B1Q;
    int n4 = NBATCH / 4;
    float mx1 = 0.0f, mxb = 0.0f;
    for (int i = blockIdx.x * blockDim.x + threadIdx.x; i < n4; i += gridDim.x * blockDim.x) {
        int c = (i / 784) & 255;
        float w = w1q[c], b = b1q[c];
        float4 v = batch4[i];
        float x0 = fmaxf(__fadd_rn(__fmul_rn(v.x, w), b), 0.0f);
        float x1 = fmaxf(__fadd_rn(__fmul_rn(v.y, w), b), 0.0f);
        float x2 = fmaxf(__fadd_rn(__fmul_rn(v.z, w), b), 0.0f);
        float x3 = fmaxf(__fadd_rn(__fmul_rn(v.w, w), b), 0.0f);
        mx1 = fmaxf(mx1, fmaxf(fmaxf(x0, x1), fmaxf(x2, x3)));
        mxb = fmaxf(mxb, fmaxf(fmaxf(fabsf(v.x), fabsf(v.y)), fmaxf(fabsf(v.z), fabsf(v.w))));
    }
    mx1 = blockReduceMax256(mx1);
    __syncthreads();
    mxb = blockReduceMax256(mxb);
    if (threadIdx.x == 0) {
        atomicMax((unsigned*)ws + 0, __float_as_uint(mx1));
        atomicMax((unsigned*)ws + 1, __float_as_uint(mxb));
    }
}

// ---------------- quantize x1 -> int8 in TRANSPOSED layout [b][hw][c] ----------------
__global__ __launch_bounds__(256) void quant1_kernel(const float4* __restrict__ batch4,
                                                     float* __restrict__ ws) {
    __shared__ unsigned ldsq[256 * 16];   // [c][hw4] packed uchar4
    const float* w1q = ws + OFF_W1Q;
    const float* b1q = ws + OFF_B1Q;
    float s_a1 = __uint_as_float(((unsigned*)ws)[0]) / 127.0f + 1e-8f;
    int b = blockIdx.x / 49, hw0 = (blockIdx.x % 49) * 64;
    int t = threadIdx.x;
    int f = t & 15, cb = t >> 4;
    #pragma unroll
    for (int j = 0; j < 16; j++) {
        int c = cb + j * 16;
        float w = w1q[c], bb = b1q[c];
        float4 v = batch4[(b * 256 + c) * 784 + (hw0 >> 2) + f];
        unsigned q0 = (unsigned)(int)clamp8(rintf(fmaxf(__fadd_rn(__fmul_rn(v.x, w), bb), 0.0f) / s_a1));
        unsigned q1 = (unsigned)(int)clamp8(rintf(fmaxf(__fadd_rn(__fmul_rn(v.y, w), bb), 0.0f) / s_a1));
        unsigned q2 = (unsigned)(int)clamp8(rintf(fmaxf(__fadd_rn(__fmul_rn(v.z, w), bb), 0.0f) / s_a1));
        unsigned q3 = (unsigned)(int)clamp8(rintf(fmaxf(__fadd_rn(__fmul_rn(v.w, w), bb), 0.0f) / s_a1));
        ldsq[c * 16 + f] = q0 | (q1 << 8) | (q2 << 16) | (q3 << 24);
    }
    __syncthreads();
    const unsigned char* l8 = (const unsigned char*)ldsq;
    uint4* outv = (uint4*)((char*)ws + X1Q_BYTE);
    int hwl = t >> 2, cq = (t & 3) * 16;
    #pragma unroll
    for (int k = 0; k < 4; k++) {
        int c0 = cq + k * 64;
        unsigned u[4] = {0u, 0u, 0u, 0u};
        #pragma unroll
        for (int i = 0; i < 16; i++) {
            unsigned by = l8[(c0 + i) * 64 + hwl];
            u[i >> 2] |= by << ((i & 3) * 8);
        }
        uint4 val; val.x = u[0]; val.y = u[1]; val.z = u[2]; val.w = u[3];
        outv[(((size_t)b * 3136 + hw0 + hwl) * 256 + c0) >> 4] = val;
    }
}

// ---------------- prep2: fold bn2 -> int bf16 weights + scales ----------------
__global__ void prep2_kernel(const float* __restrict__ c1w,
                             const float* __restrict__ g2, const float* __restrict__ b2,
                             const float* __restrict__ m2, const float* __restrict__ v2,
                             const float* __restrict__ c2w, float* __restrict__ ws) {
    int bi = blockIdx.x;
    int t = threadIdx.x;
    unsigned short* wq1b = (unsigned short*)(ws + OFF_WQ1B);
    unsigned short* w2b  = (unsigned short*)(ws + OFF_W2B);
    if (bi < BOT) {
        int o = bi;
        float tt = __fmul_rn(g2[o], 1.0f / sqrtf(v2[o] + 1e-5f));
        float wf = __fmul_rn(c1w[o * CIN + t], tt);
        float mx = blockReduceMax256(fabsf(wf));
        float s_w1 = mx / 127.0f + 1e-8f;
        float m = clamp8(rintf(wf / s_w1));
        wq1b[o * CIN + t] = bf16u(m);
        if (t == 0) {
            float s_a1 = __uint_as_float(((unsigned*)ws)[0]) / 127.0f + 1e-8f;
            ws[OFF_SC1 + o] = __fmul_rn(s_a1, s_w1);
            float bf = __fsub_rn(b2[o], __fmul_rn(m2[o], tt));
            float sb = __fmul_rn(s_a1, s_w1);
            ws[OFF_BFQ + o] = __fmul_rn(clampBig(rintf(bf / sb)), sb);
        }
    } else {
        int g = bi - BOT;
        float mx = 0.0f;
        for (int s = t; s < BOT * 9; s += 256) mx = fmaxf(mx, fabsf(c2w[g * BOT * 9 + s]));
        mx = blockReduceMax256(mx);
        float s_w2 = mx / 127.0f + 1e-8f;
        for (int s = t; s < BOT * 9; s += 256) {
            int c = s / 9, tap = s - c * 9;
            float m = clamp8(rintf(c2w[g * BOT * 9 + s] / s_w2));
            w2b[(tap * GRW + g) * BOT + c] = bf16u(m);
        }
        if (t == 0) ws[OFF_SC2 + g] = s_w2;
    }
}

// ---------------- conv1: 1x1 via bf16 MFMA, int-exact ----------------
// block tile: 64 hw x 128 o, K=256 (two slices of 128). 256 threads = 4 waves.
__global__ __launch_bounds__(256) void conv1_kernel(float* __restrict__ ws) {
    __shared__ unsigned short lA[64 * 136];    // [hw][c136] bf16 ints
    __shared__ unsigned short lW[128 * 136];   // [o][c136]  bf16 ints
    const unsigned char* x1q = (const unsigned char*)((char*)ws + X1Q_BYTE);
    const unsigned short* wq1b = (const unsigned short*)(ws + OFF_WQ1B);
    const float* sc1 = ws + OFF_SC1;
    const float* bfq = ws + OFF_BFQ;
    float* x2 = (float*)((char*)ws + X2_BYTE);
    int b = blockIdx.x / 49, hw0 = (blockIdx.x % 49) * 64;
    int t = threadIdx.x, lane = t & 63, wv = t >> 6;
    int quad = lane >> 4, l16 = lane & 15;
    int mhalf = wv & 1, nhalf = wv >> 1;
    f32x4 acc[2][4];
    #pragma unroll
    for (int i = 0; i < 2; i++)
        #pragma unroll
        for (int j = 0; j < 4; j++) acc[i][j] = (f32x4){0.f, 0.f, 0.f, 0.f};

    for (int kc = 0; kc < 256; kc += 128) {
        __syncthreads();
        {   // stage A: 64 hw x 128 c, int8 -> int-valued bf16 (uint4 = 16 bytes = 16 channels)
            int cb = t & 7, hwi = t >> 3;   // cb: 16-c block, hwi: 0..31
            #pragma unroll
            for (int r = 0; r < 2; r++) {
                int hw = hwi + r * 32;
                uint4 p = *(const uint4*)(x1q + ((size_t)b * 3136 + hw0 + hw) * 256 + kc + cb * 16);
                unsigned wd[4] = {p.x, p.y, p.z, p.w};
                bf16x8 t0, t1;
                #pragma unroll
                for (int j = 0; j < 8; j++)
                    t0[j] = (short)bf16u((float)((wd[j >> 2] >> ((j & 3) * 8)) & 255u));
                #pragma unroll
                for (int j = 0; j < 8; j++)
                    t1[j] = (short)bf16u((float)((wd[2 + (j >> 2)] >> ((j & 3) * 8)) & 255u));
                *(bf16x8*)&lA[hw * 136 + cb * 16] = t0;
                *(bf16x8*)&lA[hw * 136 + cb * 16 + 8] = t1;
            }
        }
        {   // stage W: 128 o x 128 c. BUGFIX: uint4 moves 8 ushorts -> need TWO per 16-c group
            int cb = t & 7, oi = t >> 3;    // oi 0..31
            #pragma unroll
            for (int r = 0; r < 4; r++) {
                int o = oi + r * 32;
                uint4 p0 = *(const uint4*)(wq1b + o * 256 + kc + cb * 16);
                uint4 p1 = *(const uint4*)(wq1b + o * 256 + kc + cb * 16 + 8);
                *(uint4*)&lW[o * 136 + cb * 16] = p0;
                *(uint4*)&lW[o * 136 + cb * 16 + 8] = p1;
            }
        }
        __syncthreads();
        #pragma unroll
        for (int ks = 0; ks < 4; ks++) {
            bf16x8 a0 = *(const bf16x8*)&lA[(mhalf * 32 + l16) * 136 + ks * 32 + quad * 8];
            bf16x8 a1 = *(const bf16x8*)&lA[(mhalf * 32 + 16 + l16) * 136 + ks * 32 + quad * 8];
            #pragma unroll
            for (int nt = 0; nt < 4; nt++) {
                bf16x8 bfr = *(const bf16x8*)&lW[(nhalf * 64 + nt * 16 + l16) * 136 + ks * 32 + quad * 8];
                acc[0][nt] = __builtin_amdgcn_mfma_f32_16x16x32_bf16(a0, bfr, acc[0][nt], 0, 0, 0);
                acc[1][nt] = __builtin_amdgcn_mfma_f32_16x16x32_bf16(a1, bfr, acc[1][nt], 0, 0, 0);
            }
        }
    }
    float mx = 0.0f;
    #pragma unroll
    for (int nt = 0; nt < 4; nt++) {
        int o = nhalf * 64 + nt * 16 + l16;
        float s = sc1[o], bb = bfq[o];
        #pragma unroll
        for (int mt = 0; mt < 2; mt++) {
            int hw = hw0 + mhalf * 32 + mt * 16 + quad * 4;
            float4 v;
            v.x = fmaxf(__fadd_rn(__fmul_rn(acc[mt][nt][0], s), bb), 0.0f);
            v.y = fmaxf(__fadd_rn(__fmul_rn(acc[mt][nt][1], s), bb), 0.0f);
            v.z = fmaxf(__fadd_rn(__fmul_rn(acc[mt][nt][2], s), bb), 0.0f);
            v.w = fmaxf(__fadd_rn(__fmul_rn(acc[mt][nt][3], s), bb), 0.0f);
            mx = fmaxf(mx, fmaxf(fmaxf(v.x, v.y), fmaxf(v.z, v.w)));
            *(float4*)&x2[(size_t)(b * BOT + o) * HW + hw] = v;
        }
    }
    mx = waveReduceMax(mx);
    if (lane == 0) atomicMax((unsigned*)ws + 2, __float_as_uint(mx));
}

// ---------------- conv2: 3x3 via tap-decomposed bf16 MFMA, int-exact ----------------
// block: 2 output rows x 64 x-positions (56 valid) x 32 g. 128 threads = 2 waves (one row each).
__global__ __launch_bounds__(128) void conv2_kernel(float* __restrict__ ws) {
    __shared__ unsigned short xt[4 * 66 * 40];   // [row][xslot][c40] bf16 ints (zero-padded halo)
    __shared__ unsigned short wt[9 * 32 * 40];   // [tap*32+g][c40]
    const float* x2 = (const float*)((char*)ws + X2_BYTE);
    const unsigned short* w2b = (const unsigned short*)(ws + OFF_W2B);
    const float* sc2 = ws + OFF_SC2;
    float* x3 = (float*)((char*)ws + X3_BYTE);
    int b = blockIdx.x / 28, h0 = (blockIdx.x % 28) * 2;
    int t = threadIdx.x, lane = t & 63, r = t >> 6;   // r = output row within block
    int quad = lane >> 4, l16 = lane & 15;
    float s_a2 = __uint_as_float(((unsigned*)ws)[2]) / 127.0f + 1e-8f;
    float rinv = 1.0f / s_a2;
    f32x4 acc[4][2];
    #pragma unroll
    for (int i = 0; i < 4; i++) { acc[i][0] = (f32x4){0.f,0.f,0.f,0.f}; acc[i][1] = (f32x4){0.f,0.f,0.f,0.f}; }

    // zero the x tile once (halo/pad slots stay zero across c-slices)
    for (int s = t; s < 4 * 66 * 40 * 2 / 16; s += 128) {
        uint4 z; z.x = z.y = z.z = z.w = 0u;
        ((uint4*)xt)[s] = z;
    }

    for (int cs = 0; cs < 4; cs++) {
        __syncthreads();
        // stage weights: [tap][g][32 c] for this c-slice. BUGFIX: 4 quarters of 8 ushorts each.
        for (int s = t; s < 1152; s += 128) {
            int gi = s >> 2, q = s & 3;
            uint4 p = *(const uint4*)(w2b + gi * BOT + cs * 32 + q * 8);
            *(uint4*)&wt[gi * 40 + q * 8] = p;
        }
        // stage x tile: rows h0-1..h0+2, w 0..55, quantize on the fly
        for (int s = t; s < 1792; s += 128) {
            int w4 = s % 14, rc = s / 14;
            int row = rc & 3, c = rc >> 2;
            int h = h0 - 1 + row;
            if (h >= 0 && h < 56) {
                float4 v = *(const float4*)&x2[(size_t)(b * BOT + cs * 32 + c) * HW + h * 56 + w4 * 4];
                int base = (row * 66 + w4 * 4 + 1) * 40 + c;
                xt[base]       = bf16u(clamp8(rintf(v.x * rinv)));
                xt[base + 40]  = bf16u(clamp8(rintf(v.y * rinv)));
                xt[base + 80]  = bf16u(clamp8(rintf(v.z * rinv)));
                xt[base + 120] = bf16u(clamp8(rintf(v.w * rinv)));
            }
        }
        __syncthreads();
        #pragma unroll
        for (int tap = 0; tap < 9; tap++) {
            int dh = tap / 3, dw = tap % 3;        // 0..2
            int lrow = r + dh;                     // r + dh - 1 + 1
            bf16x8 b0 = *(const bf16x8*)&wt[(tap * 32 + l16) * 40 + quad * 8];
            bf16x8 b1 = *(const bf16x8*)&wt[(tap * 32 + 16 + l16) * 40 + quad * 8];
            #pragma unroll
            for (int mt = 0; mt < 4; mt++) {
                int xslot = mt * 16 + l16 + dw;    // + dw - 1 + 1
                bf16x8 a = *(const bf16x8*)&xt[(lrow * 66 + xslot) * 40 + quad * 8];
                acc[mt][0] = __builtin_amdgcn_mfma_f32_16x16x32_bf16(a, b0, acc[mt][0], 0, 0, 0);
                acc[mt][1] = __builtin_amdgcn_mfma_f32_16x16x32_bf16(a, b1, acc[mt][1], 0, 0, 0);
            }
        }
    }
    float mx = 0.0f;
    #pragma unroll
    for (int nt = 0; nt < 2; nt++) {
        int g = nt * 16 + l16;
        float s2 = __fmul_rn(s_a2, sc2[g]);
        #pragma unroll
        for (int mt = 0; mt < 4; mt++) {
            int xb = mt * 16 + quad * 4;
            if (xb < 56) {
                float4 v;
                v.x = __fmul_rn(acc[mt][nt][0], s2);
                v.y = __fmul_rn(acc[mt][nt][1], s2);
                v.z = __fmul_rn(acc[mt][nt][2], s2);
                v.w = __fmul_rn(acc[mt][nt][3], s2);
                mx = fmaxf(mx, fmaxf(fmaxf(fabsf(v.x), fabsf(v.y)), fmaxf(fabsf(v.z), fabsf(v.w))));
                *(float4*)&x3[(size_t)(b * GRW + g) * HW + (h0 + r) * 56 + xb] = v;
            }
        }
    }
    mx = waveReduceMax(mx);
    if (lane == 0) atomicMax((unsigned*)ws + 3, __float_as_uint(mx));
}

// ---------------- output: concat + fake-quant ----------------
__global__ __launch_bounds__(256) void outq_kernel(const float4* __restrict__ batch4,
                                                   const float* __restrict__ ws,
                                                   float* __restrict__ out) {
    const float4* x34 = (const float4*)((const char*)ws + X3_BYTE);
    float maxb = __uint_as_float(((const unsigned*)ws)[1]);
    float max3 = __uint_as_float(((const unsigned*)ws)[3]);
    float s_out = fmaxf(maxb, max3) / 127.0f + 1e-8f;
    float4* out4 = (float4*)out;
    int n4 = NOUT / 4;
    for (int i = blockIdx.x * blockDim.x + threadIdx.x; i < n4; i += gridDim.x * blockDim.x) {
        int chl = i / 784;
        int b = chl / COUT;
        int ch = chl - b * COUT;
        int hw4 = i - chl * 784;
        float4 v;
        if (ch < CIN) v = batch4[(b * CIN + ch) * 784 + hw4];
        else          v = x34[(b * GRW + (ch - CIN)) * 784 + hw4];
        float4 r;
        r.x = __fmul_rn(clamp8(rintf(v.x / s_out)), s_out);
        r.y = __fmul_rn(clamp8(rintf(v.y / s_out)), s_out);
        r.z = __fmul_rn(clamp8(rintf(v.z / s_out)), s_out);
        r.w = __fmul_rn(clamp8(rintf(v.w / s_out)), s_out);
        out4[i] = r;
    }
    if (blockIdx.x == 0 && threadIdx.x == 0) out[NOUT] = s_out;
}

extern "C" void kernel_launch(void* const* d_in, const int* in_sizes, int n_in,
                              void* d_out, int out_size, void* d_ws, size_t ws_size,
                              hipStream_t stream) {
    const float* batch = (const float*)d_in[0];
    const float* s_in  = (const float*)d_in[1];
    const float* g1    = (const float*)d_in[2];
    const float* b1    = (const float*)d_in[3];
    const float* m1    = (const float*)d_in[4];
    const float* v1    = (const float*)d_in[5];
    const float* c1w   = (const float*)d_in[6];
    const float* g2    = (const float*)d_in[7];
    const float* b2    = (const float*)d_in[8];
    const float* m2    = (const float*)d_in[9];
    const float* v2    = (const float*)d_in[10];
    const float* c2w   = (const float*)d_in[11];
    float* out = (float*)d_out;
    float* ws  = (float*)d_ws;

    hipLaunchKernelGGL(prep1_kernel, dim3(1), dim3(256), 0, stream, g1, b1, m1, v1, s_in, ws);
    hipLaunchKernelGGL(max1_kernel, dim3(4096), dim3(256), 0, stream, (const float4*)batch, ws);
    hipLaunchKernelGGL(quant1_kernel, dim3(32 * 49), dim3(256), 0, stream, (const float4*)batch, ws);
    hipLaunchKernelGGL(prep2_kernel, dim3(160), dim3(256), 0, stream, c1w, g2, b2, m2, v2, c2w, ws);
    hipLaunchKernelGGL(conv1_kernel, dim3(32 * 49), dim3(256), 0, stream, ws);
    hipLaunchKernelGGL(conv2_kernel, dim3(32 * 28), dim3(128), 0, stream, ws);
    hipLaunchKernelGGL(outq_kernel, dim3(4096), dim3(256), 0, stream, (const float4*)batch, ws, out);
}